// Round 4
// baseline (120.435 us; speedup 1.0000x reference)
//
#include <hip/hip_runtime.h>

// RandomAffine via 2-D tiled LDS staging.
// Each 256-thread block computes a 32x32 output tile. The affine preimage of
// the tile is a rotated rect; we stage its integer bounding box (<=47x47 px,
// capacity 52x52) in LDS with coalesced loads, applying reflect-2048 during
// the fill. Bilinear sampling then reads LDS only, with no per-pixel reflect
// (local ix+1 / iy+1 are contiguous because every bbox slot holds the
// reflected image value for that unreflected integer coordinate).

#define IMG_H 2048
#define IMG_W 2048
#define TILE  32
#define BBH   52
#define BBW   52
#define BBW3  (BBW * 3)          // 156 floats per staged row
#define BBN   (BBH * BBW3)       // 8112 floats = 32448 B LDS

__device__ __forceinline__ int reflect2048(int i) {
    // scipy 'reflect' (duplicate-edge), period 2n, n=2048: mask works for
    // negatives down to -4096 (coords here stay within ~±1500).
    int p = i & 4095;
    return (p < 2048) ? p : (4095 - p);
}

__global__ __launch_bounds__(256) void affine_tile_kernel(
    const float* __restrict__ img, const float* __restrict__ Mp,
    float* __restrict__ out)
{
    __shared__ float lds[BBN];

    const int tid = threadIdx.x;
    const int tbx = blockIdx.x & 63;     // W/TILE = 64 tiles per row
    const int tby = blockIdx.x >> 6;
    const int i0 = tby * TILE, j0 = tbx * TILE;

    const float step = 2048.0f / 2047.0f;
    const float m00 = Mp[0], m01 = Mp[1];
    const float m10 = Mp[3], m11 = Mp[4];
    const float b0 = Mp[6] + 1024.0f, b1 = Mp[7] + 1024.0f;

    // Source coords at the 4 tile corners (affine -> extremes at corners).
    const float yv0 = fmaf((float)i0,            step, -1024.0f);
    const float yv1 = fmaf((float)(i0 + TILE-1), step, -1024.0f);
    const float xv0 = fmaf((float)j0,            step, -1024.0f);
    const float xv1 = fmaf((float)(j0 + TILE-1), step, -1024.0f);

    const float rya = yv0*m00 + xv0*m10 + b0, ryb = yv0*m00 + xv1*m10 + b0;
    const float ryc = yv1*m00 + xv0*m10 + b0, ryd = yv1*m00 + xv1*m10 + b0;
    const float rxa = yv0*m01 + xv0*m11 + b1, rxb = yv0*m01 + xv1*m11 + b1;
    const float rxc = yv1*m01 + xv0*m11 + b1, rxd = yv1*m01 + xv1*m11 + b1;

    const float min_ry = fminf(fminf(rya, ryb), fminf(ryc, ryd));
    const float min_rx = fminf(fminf(rxa, rxb), fminf(rxc, rxd));

    // -1 margin absorbs fp wobble of interior pixels vs corner extremes.
    const int y0 = (int)floorf(min_ry) - 1;
    const int x0 = (int)floorf(min_rx) - 1;

    // ---- Stage bbox into LDS (coalesced in the interior; reflect at edges).
    for (int e = tid; e < BBN; e += 256) {
        int byy = e / BBW3;
        int k   = e - byy * BBW3;
        int xx  = k / 3;
        int ch  = k - xx * 3;
        int gy  = reflect2048(y0 + byy);
        int gx  = reflect2048(x0 + xx);
        lds[e] = img[(gy * IMG_W + gx) * 3 + ch];
    }
    __syncthreads();

    // ---- 4 pixels per thread: 8 rows x 32 cols per iteration.
    #pragma unroll
    for (int r = 0; r < 4; ++r) {
        const int li = r * 8 + (tid >> 5);
        const int lj = tid & 31;
        const int i = i0 + li, j = j0 + lj;

        const float yv = fmaf((float)i, step, -1024.0f);
        const float xv = fmaf((float)j, step, -1024.0f);
        const float ry = yv*m00 + xv*m10 + b0;
        const float rx = yv*m01 + xv*m11 + b1;

        const float fy = floorf(ry), fx = floorf(rx);
        const float wy1 = ry - fy, wx1 = rx - fx;
        const float wy0 = 1.0f - wy1, wx0 = 1.0f - wx1;

        const int iy = (int)fy - y0;
        const int ix = (int)fx - x0;

        const float* p0 = &lds[iy * BBW3 + ix * 3];
        const float* p1 = p0 + BBW3;

        const float w00 = wy0*wx0, w01 = wy0*wx1;
        const float w10 = wy1*wx0, w11 = wy1*wx1;

        const int o = (i * IMG_W + j) * 3;
        out[o + 0] = w00*p0[0] + w01*p0[3] + w10*p1[0] + w11*p1[3];
        out[o + 1] = w00*p0[1] + w01*p0[4] + w10*p1[1] + w11*p1[4];
        out[o + 2] = w00*p0[2] + w01*p0[5] + w10*p1[2] + w11*p1[5];
    }
}

extern "C" void kernel_launch(void* const* d_in, const int* in_sizes, int n_in,
                              void* d_out, int out_size, void* d_ws, size_t ws_size,
                              hipStream_t stream) {
    const float* img = (const float*)d_in[0];   // (2048,2048,3) f32
    const float* M   = (const float*)d_in[1];   // (3,3) f32 row-major
    float* out = (float*)d_out;                 // (2048,2048,3) f32

    dim3 grid((IMG_H / TILE) * (IMG_W / TILE)), block(256);
    hipLaunchKernelGGL(affine_tile_kernel, grid, block, 0, stream, img, M, out);
}

// Round 6
// 119.589 us; speedup vs baseline: 1.0071x; 1.0071x over previous
//
#include <hip/hip_runtime.h>

// RandomAffine via 2-D tiled LDS staging, vectorized fill.
// Each 256-thread block computes a 32x32 output tile. The integer bounding
// box of the tile's affine preimage (<=50x47 px incl. alignment, capacity
// 52x52) is staged in LDS. x0 is aligned to 4 px so each staged row is a
// contiguous, 16B-aligned 624B strip of a (y-reflected) image row ->
// float4 row copies, no integer division. Tiles whose x-range crosses the
// image border take a per-element reflect path.

#define IMG_H 2048
#define IMG_W 2048
#define TILE  32
#define BBH   52
#define BBW   52
#define BBW3  (BBW * 3)          // 156 floats per staged row (624 B)
#define ROWV4 (BBW3 / 4)         // 39 float4 per row

__device__ __forceinline__ int reflect2048(int i) {
    // scipy 'reflect' (duplicate-edge), period 2n, n=2048.
    int p = i & 4095;
    return (p < 2048) ? p : (4095 - p);
}

__global__ __launch_bounds__(256) void affine_tile_kernel(
    const float* __restrict__ img, const float* __restrict__ Mp,
    float* __restrict__ out)
{
    __shared__ float lds[BBH * BBW3];

    const int tid = threadIdx.x;
    const int tbx = blockIdx.x & 63;     // W/TILE = 64 tiles per row
    const int tby = blockIdx.x >> 6;
    const int i0 = tby * TILE, j0 = tbx * TILE;

    const float step = 2048.0f / 2047.0f;
    const float m00 = Mp[0], m01 = Mp[1];
    const float m10 = Mp[3], m11 = Mp[4];
    const float b0 = Mp[6] + 1024.0f, b1 = Mp[7] + 1024.0f;

    // Source coords at the 4 tile corners (affine -> extremes at corners).
    const float yv0 = fmaf((float)i0,            step, -1024.0f);
    const float yv1 = fmaf((float)(i0 + TILE-1), step, -1024.0f);
    const float xv0 = fmaf((float)j0,            step, -1024.0f);
    const float xv1 = fmaf((float)(j0 + TILE-1), step, -1024.0f);

    const float rya = yv0*m00 + xv0*m10 + b0, ryb = yv0*m00 + xv1*m10 + b0;
    const float ryc = yv1*m00 + xv0*m10 + b0, ryd = yv1*m00 + xv1*m10 + b0;
    const float rxa = yv0*m01 + xv0*m11 + b1, rxb = yv0*m01 + xv1*m11 + b1;
    const float rxc = yv1*m01 + xv0*m11 + b1, rxd = yv1*m01 + xv1*m11 + b1;

    const float min_ry = fminf(fminf(rya, ryb), fminf(ryc, ryd));
    const float min_rx = fminf(fminf(rxa, rxb), fminf(rxc, rxd));

    // -1 margin absorbs fp wobble; x0 aligned down to 4 px so that
    // (gy*2048 + x0)*3 floats is 16B-aligned (x0 % 4 == 0 => 3*x0 % 4 == 0).
    const int y0 = (int)floorf(min_ry) - 1;
    const int x0 = ((int)floorf(min_rx) - 1) & ~3;

    // ---- Stage bbox into LDS.
    if (x0 >= 0 && x0 + BBW <= IMG_W) {
        // Fast path: each staged row is contiguous in the image.
        const int wid = tid >> 6, lane = tid & 63;
        if (lane < ROWV4) {
            #pragma unroll
            for (int r = wid; r < BBH; r += 4) {
                const int gy = reflect2048(y0 + r);
                const float4 v = *(const float4*)(img + gy * (IMG_W*3) + x0*3 + lane*4);
                *(float4*)&lds[r * BBW3 + lane * 4] = v;
            }
        }
    } else {
        // Border tiles: per-element x reflect (const-divisor div is cheap).
        for (int e = tid; e < BBH * BBW; e += 256) {
            const int r  = e / BBW;
            const int xx = e - r * BBW;
            const int gy = reflect2048(y0 + r);
            const int gx = reflect2048(x0 + xx);
            const float* s = img + (gy * IMG_W + gx) * 3;
            float* d = &lds[r * BBW3 + xx * 3];
            d[0] = s[0]; d[1] = s[1]; d[2] = s[2];
        }
    }
    __syncthreads();

    // ---- 4 pixels per thread: 8 rows x 32 cols per iteration.
    #pragma unroll
    for (int r = 0; r < 4; ++r) {
        const int li = r * 8 + (tid >> 5);
        const int lj = tid & 31;
        const int i = i0 + li, j = j0 + lj;

        const float yv = fmaf((float)i, step, -1024.0f);
        const float xv = fmaf((float)j, step, -1024.0f);
        const float ry = yv*m00 + xv*m10 + b0;
        const float rx = yv*m01 + xv*m11 + b1;

        const float fy = floorf(ry), fx = floorf(rx);
        const float wy1 = ry - fy, wx1 = rx - fx;
        const float wy0 = 1.0f - wy1, wx0 = 1.0f - wx1;

        const int iy = (int)fy - y0;
        const int ix = (int)fx - x0;

        const float* p0 = &lds[iy * BBW3 + ix * 3];
        const float* p1 = p0 + BBW3;

        const float w00 = wy0*wx0, w01 = wy0*wx1;
        const float w10 = wy1*wx0, w11 = wy1*wx1;

        const int o = (i * IMG_W + j) * 3;
        out[o + 0] = w00*p0[0] + w01*p0[3] + w10*p1[0] + w11*p1[3];
        out[o + 1] = w00*p0[1] + w01*p0[4] + w10*p1[1] + w11*p1[4];
        out[o + 2] = w00*p0[2] + w01*p0[5] + w10*p1[2] + w11*p1[5];
    }
}

extern "C" void kernel_launch(void* const* d_in, const int* in_sizes, int n_in,
                              void* d_out, int out_size, void* d_ws, size_t ws_size,
                              hipStream_t stream) {
    const float* img = (const float*)d_in[0];   // (2048,2048,3) f32
    const float* M   = (const float*)d_in[1];   // (3,3) f32 row-major
    float* out = (float*)d_out;                 // (2048,2048,3) f32

    dim3 grid((IMG_H / TILE) * (IMG_W / TILE)), block(256);
    hipLaunchKernelGGL(affine_tile_kernel, grid, block, 0, stream, img, M, out);
}

// Round 9
// 105.300 us; speedup vs baseline: 1.1437x; 1.1357x over previous
//
#include <hip/hip_runtime.h>
#include <stdint.h>

// RandomAffine via 2-D tiled LDS staging with global_load_lds fill.
// Each 256-thread block computes a 32x32 output tile. The integer bbox of
// the tile's affine preimage is staged in LDS via direct global->LDS DMA
// (no VGPR round-trip; ~13 loads in flight per wave, drained once at the
// barrier). x0 is 4px-aligned so every staged row is a 16B-aligned
// contiguous strip of a (y-reflected) image row. Border tiles (x range
// crossing the image edge) take a scalar per-element reflect path.

#define IMG_H 2048
#define IMG_W 2048
#define TILE  32
#define BBH   52
#define BBW   52
#define BBW3  (BBW * 3)          // 156 floats per staged row (624 B)

__device__ __forceinline__ int reflect2048(int i) {
    // scipy 'reflect' (duplicate-edge), period 2n, n=2048.
    int p = i & 4095;
    return (p < 2048) ? p : (4095 - p);
}

__device__ __forceinline__ void gl2lds16(const float* g, float* l) {
    // 16B per lane, LDS dest = wave-uniform base + lane*16 (HW rule).
    __builtin_amdgcn_global_load_lds(
        (const __attribute__((address_space(1))) void*)g,
        (__attribute__((address_space(3))) void*)l,
        16, 0, 0);
}

__global__ __launch_bounds__(256) void affine_tile_kernel(
    const float* __restrict__ img, const float* __restrict__ Mp,
    float* __restrict__ out)
{
    __shared__ float lds[BBH * BBW3];

    const int tid = threadIdx.x;
    const int tbx = blockIdx.x & 63;     // W/TILE = 64 tiles per row
    const int tby = blockIdx.x >> 6;
    const int i0 = tby * TILE, j0 = tbx * TILE;

    const float step = 2048.0f / 2047.0f;
    const float m00 = Mp[0], m01 = Mp[1];
    const float m10 = Mp[3], m11 = Mp[4];
    const float b0 = Mp[6] + 1024.0f, b1 = Mp[7] + 1024.0f;

    // Source coords at the 4 tile corners (affine -> extremes at corners).
    const float yv0 = fmaf((float)i0,            step, -1024.0f);
    const float yv1 = fmaf((float)(i0 + TILE-1), step, -1024.0f);
    const float xv0 = fmaf((float)j0,            step, -1024.0f);
    const float xv1 = fmaf((float)(j0 + TILE-1), step, -1024.0f);

    const float rya = yv0*m00 + xv0*m10 + b0, ryb = yv0*m00 + xv1*m10 + b0;
    const float ryc = yv1*m00 + xv0*m10 + b0, ryd = yv1*m00 + xv1*m10 + b0;
    const float rxa = yv0*m01 + xv0*m11 + b1, rxb = yv0*m01 + xv1*m11 + b1;
    const float rxc = yv1*m01 + xv0*m11 + b1, rxd = yv1*m01 + xv1*m11 + b1;

    const float min_ry = fminf(fminf(rya, ryb), fminf(ryc, ryd));
    const float max_ry = fmaxf(fmaxf(rya, ryb), fmaxf(ryc, ryd));
    const float min_rx = fminf(fminf(rxa, rxb), fminf(rxc, rxd));
    const float max_rx = fmaxf(fmaxf(rxa, rxb), fmaxf(rxc, rxd));

    // Margins: -1/+2 absorb fp wobble + the +1 bilinear neighbor.
    const int y0 = (int)floorf(min_ry) - 1;
    const int nrows = (int)floorf(max_ry) + 2 - y0 + 1;          // <= 48
    const int x0 = ((int)floorf(min_rx) - 1) & ~3;               // 16B align
    const int xw = (int)floorf(max_rx) + 2 - x0 + 1;             // <= 51
    const int nv4 = (xw * 3 + 3) >> 2;                           // <= 39

    // ---- Stage bbox into LDS.
    if (x0 >= 0 && x0 * 3 + nv4 * 4 <= IMG_W * 3) {
        // Fast path: each staged row is a contiguous 16B-aligned strip.
        const int wid = tid >> 6, lane = tid & 63;
        if (lane < nv4) {
            for (int r = wid; r < nrows; r += 4) {
                const int gy = reflect2048(y0 + r);
                gl2lds16(img + gy * (IMG_W*3) + x0*3 + lane*4, &lds[r * BBW3]);
            }
        }
    } else {
        // Border tiles: per-element x reflect (const-divisor div is cheap).
        for (int e = tid; e < nrows * BBW; e += 256) {
            const int r  = e / BBW;
            const int xx = e - r * BBW;
            const int gy = reflect2048(y0 + r);
            const int gx = reflect2048(x0 + xx);
            const float* s = img + (gy * IMG_W + gx) * 3;
            float* d = &lds[r * BBW3 + xx * 3];
            d[0] = s[0]; d[1] = s[1]; d[2] = s[2];
        }
    }
    __syncthreads();   // compiler drains vmcnt(0) here -> LDS valid

    // ---- 4 pixels per thread: 8 rows x 32 cols per iteration.
    #pragma unroll
    for (int r = 0; r < 4; ++r) {
        const int li = r * 8 + (tid >> 5);
        const int lj = tid & 31;
        const int i = i0 + li, j = j0 + lj;

        const float yv = fmaf((float)i, step, -1024.0f);
        const float xv = fmaf((float)j, step, -1024.0f);
        const float ry = yv*m00 + xv*m10 + b0;
        const float rx = yv*m01 + xv*m11 + b1;

        const float fy = floorf(ry), fx = floorf(rx);
        const float wy1 = ry - fy, wx1 = rx - fx;
        const float wy0 = 1.0f - wy1, wx0 = 1.0f - wx1;

        const int iy = (int)fy - y0;
        const int ix = (int)fx - x0;

        const float* p0 = &lds[iy * BBW3 + ix * 3];
        const float* p1 = p0 + BBW3;

        const float w00 = wy0*wx0, w01 = wy0*wx1;
        const float w10 = wy1*wx0, w11 = wy1*wx1;

        const int o = (i * IMG_W + j) * 3;
        out[o + 0] = w00*p0[0] + w01*p0[3] + w10*p1[0] + w11*p1[3];
        out[o + 1] = w00*p0[1] + w01*p0[4] + w10*p1[1] + w11*p1[4];
        out[o + 2] = w00*p0[2] + w01*p0[5] + w10*p1[2] + w11*p1[5];
    }
}

extern "C" void kernel_launch(void* const* d_in, const int* in_sizes, int n_in,
                              void* d_out, int out_size, void* d_ws, size_t ws_size,
                              hipStream_t stream) {
    const float* img = (const float*)d_in[0];   // (2048,2048,3) f32
    const float* M   = (const float*)d_in[1];   // (3,3) f32 row-major
    float* out = (float*)d_out;                 // (2048,2048,3) f32

    dim3 grid((IMG_H / TILE) * (IMG_W / TILE)), block(256);
    hipLaunchKernelGGL(affine_tile_kernel, grid, block, 0, stream, img, M, out);
}